// Round 2
// baseline (166.522 us; speedup 1.0000x reference)
//
#include <hip/hip_runtime.h>
#include <hip/hip_bf16.h>
#include <stdint.h>

typedef __attribute__((ext_vector_type(8))) short s16x8;
typedef __attribute__((ext_vector_type(4))) float f32x4;

#define T_   2048
#define NH   16
#define HD   64
#define DIN  1024
#define SCALE_LOG2 0.18033688011112042f  // (1/8)*log2(e)

#define MFMA32(a, b, c) __builtin_amdgcn_mfma_f32_16x16x32_bf16(a, b, c, 0, 0, 0)

// RTNE fp32 -> bf16
__device__ __forceinline__ unsigned short f2bf(float f) {
  union { float f; uint32_t u; } c; c.f = f;
  uint32_t u = c.u;
  return (unsigned short)((u + 0x7FFFu + ((u >> 16) & 1u)) >> 16);
}

__device__ __forceinline__ uint32_t pk_bf16(float a, float b) {
  __hip_bfloat162 h = __float22bfloat162_rn(make_float2(a, b));
  return *reinterpret_cast<uint32_t*>(&h);
}

// async global->LDS, 16B per lane; dest = wave-uniform base + lane*16
#define GLL(gp, lp) __builtin_amdgcn_global_load_lds( \
    (__attribute__((address_space(1))) void*)(gp),    \
    (__attribute__((address_space(3))) void*)(lp), 16, 0, 0)

// ---------------- kernel 1: fp32 -> bf16 conversion ----------------
__global__ __launch_bounds__(256) void cvt_kernel(
    const float* __restrict__ x,  const float* __restrict__ wq,
    const float* __restrict__ wk, const float* __restrict__ wv,
    unsigned short* __restrict__ xb, unsigned short* __restrict__ wb) {
  int i = (blockIdx.x * 256 + threadIdx.x) * 4;
  float4 v;
  unsigned short* dp;
  if (i < 4194304) {
    v = *(const float4*)(x + i);
    dp = xb + i;
  } else {
    int j = i - 4194304;
    int seg = j >> 20, r = j & 1048575;
    const float* w = (seg == 0) ? wq : (seg == 1) ? wk : wv;
    v = *(const float4*)(w + r);
    dp = wb + j;
  }
  ushort4 o;
  o.x = f2bf(v.x); o.y = f2bf(v.y); o.z = f2bf(v.z); o.w = f2bf(v.w);
  *(ushort4*)dp = o;
}

// ---------------- kernel 2: QKV projection GEMM ----------------
// 64x128 (MxN) tiles -> grid 24x64 = 1536 blocks = 6 blocks/CU (was 3:
// grid-starved, MfmaUtil 17 / Occ 13 with all pipes idle = latency-bound).
// LDS 24KB/block = exactly 6 resident; acc 32 VGPR/wave. XOR-swizzled LDS,
// all-b128, GLL staging. Epilogue: Q pre-scaled; V transposed [bh][d][t].
__global__ __launch_bounds__(256) void qkv_gemm(
    const unsigned short* __restrict__ A, const unsigned short* __restrict__ Bm,
    unsigned short* __restrict__ qkv) {
  __shared__ __attribute__((aligned(16))) unsigned short Alds[64 * 64];
  __shared__ __attribute__((aligned(16))) unsigned short Blds[128 * 64];
  const int tid = threadIdx.x;
  const int lane = tid & 63, wave = tid >> 6;
  const int wm = wave >> 1, wn = wave & 1;  // 2x2 waves over 64x128
  const int m0 = blockIdx.y * 64, n0 = blockIdx.x * 128;

  f32x4 acc[2][4] = {};

  const int srA = wave * 16 + (lane >> 3);  // A staging row (2 issues x 8)
  const int srB = wave * 32 + (lane >> 3);  // B staging row (4 issues x 8)
  const int scol = (((lane & 7) ^ ((lane >> 3) & 7))) * 8;
  const unsigned short* ag = A  + (size_t)(m0 + srA) * DIN + scol;
  const unsigned short* bg = Bm + (size_t)(n0 + srB) * DIN + scol;
  unsigned short* al = &Alds[wave * 16 * 64];
  unsigned short* bl = &Blds[wave * 32 * 64];

  const int l16 = lane & 15, quad = lane >> 4;
  const int sw = l16 & 7;

  for (int k0 = 0; k0 < DIN; k0 += 64) {
    __syncthreads();
#pragma unroll
    for (int i = 0; i < 2; i++)
      GLL(ag + (size_t)i * 8 * DIN + k0, al + i * 512);
#pragma unroll
    for (int i = 0; i < 4; i++)
      GLL(bg + (size_t)i * 8 * DIN + k0, bl + i * 512);
    __syncthreads();
#pragma unroll
    for (int ks = 0; ks < 2; ks++) {
      const int cl = ((ks * 4 + quad) ^ sw) * 8;
      s16x8 af[2], bf[4];
#pragma unroll
      for (int mt = 0; mt < 2; mt++)
        af[mt] = *(const s16x8*)&Alds[(wm * 32 + mt * 16 + l16) * 64 + cl];
#pragma unroll
      for (int nt = 0; nt < 4; nt++)
        bf[nt] = *(const s16x8*)&Blds[(wn * 64 + nt * 16 + l16) * 64 + cl];
#pragma unroll
      for (int mt = 0; mt < 2; mt++)
#pragma unroll
        for (int nt = 0; nt < 4; nt++)
          acc[mt][nt] = MFMA32(af[mt], bf[nt], acc[mt][nt]);
    }
  }

#pragma unroll
  for (int mt = 0; mt < 2; mt++) {
    int mbase = m0 + wm * 32 + mt * 16 + (quad << 2);
    int b = mbase >> 11, t = mbase & 2047;
#pragma unroll
    for (int nt = 0; nt < 4; nt++) {
      int n = n0 + wn * 64 + nt * 16 + l16;
      int sel = n >> 10, h = (n >> 6) & 15, d = n & 63;
      int bh = b * NH + h;
      if (sel == 2) {
        ushort4 pk;
        pk.x = f2bf(acc[mt][nt][0]); pk.y = f2bf(acc[mt][nt][1]);
        pk.z = f2bf(acc[mt][nt][2]); pk.w = f2bf(acc[mt][nt][3]);
        *(ushort4*)&qkv[8388608 + (size_t)(bh * HD + d) * T_ + t] = pk;
      } else {
        float qs = (sel == 0) ? SCALE_LOG2 : 1.f;  // fold softmax scale into Q
#pragma unroll
        for (int r = 0; r < 4; r++)
          qkv[(size_t)sel * 4194304 + (size_t)(bh * T_ + t + r) * HD + d] =
              f2bf(acc[mt][nt][r] * qs);
      }
    }
  }
}

// ---------------- kernel 3: causal flash attention (v2) ----------------
// LDS-throughput fix: 2 waves x 32 q (was 4 x 16) -- halves per-wave K/V
// tile re-reads per q-row (the dominant LDS term: full 16-b128 K+V read
// per wave amortized over 2x the q). K/V staged via double-buffered
// global_load_lds with pre-swizzled per-lane SOURCE addresses (LDS dest
// linear, same XOR swizzle seen by the b128 readers). One barrier per
// k-tile: top-of-loop __syncthreads (implicit vmcnt(0)+lgkmcnt(0) drain)
// publishes buf[cur] and retires last iter's reads of buf[cur^1]; next
// tile's GLLs issue right after, hiding global latency under the whole
// compute phase. LDS 40KB -> 4 blocks/CU, grid 1024 x 128thr (qt
// descending for load balance).
__global__ __launch_bounds__(128) void attn_kernel(
    const unsigned short* __restrict__ qkv, float* __restrict__ out) {
  __shared__ __attribute__((aligned(16))) unsigned short Klds[2][64 * 64];
  __shared__ __attribute__((aligned(16))) unsigned short Vt[2][64 * 64];
  __shared__ __attribute__((aligned(16))) unsigned short Plds[64 * 64];

  const int lane = threadIdx.x & 63, wave = threadIdx.x >> 6;
  const int l16 = lane & 15, quad = lane >> 4;
  const int swl = l16 & 7;
  const int qt = 31 - blockIdx.y, bh = blockIdx.x;
  const int q0 = qt * 64;
  const size_t bh_off = (size_t)bh * (T_ * HD);
  const unsigned short* Q  = qkv + bh_off;            // [t][d], pre-scaled
  const unsigned short* Kb = qkv + 4194304 + bh_off;  // [t][d]
  const unsigned short* Vb = qkv + 8388608 + bh_off;  // [d][t]

  // Q fragments: 32 q-rows per wave (B-operand, n = q)
  s16x8 qf[2][2];
#pragma unroll
  for (int nt = 0; nt < 2; nt++) {
    const unsigned short* qp =
        Q + (size_t)(q0 + wave * 32 + nt * 16 + l16) * HD + quad * 8;
    qf[nt][0] = *(const s16x8*)(qp);
    qf[nt][1] = *(const s16x8*)(qp + 32);
  }

  // GLL staging: wave w covers rows w*32..w*32+31 of K (t-rows) and V
  // (d-rows). Per GLL i: row = w*32+i*8+(lane>>3), LDS phys chunk lane&7;
  // source col chunk pre-swizzled = (lane&7)^(lane>>3) (row&7 == lane>>3).
  const int r8 = lane >> 3;
  const int xc = ((lane & 7) ^ r8) * 8;
  const unsigned short* kg = Kb + (size_t)(wave * 32 + r8) * HD + xc;
  const unsigned short* vg = Vb + (size_t)(wave * 32 + r8) * T_ + xc;
  const int sbase = wave * 32 * 64;

  const s16x8 onesf = {0x3F80, 0x3F80, 0x3F80, 0x3F80,
                       0x3F80, 0x3F80, 0x3F80, 0x3F80};  // bf16 1.0 x8
  f32x4 o[2][4] = {};
  f32x4 lacc[2] = {};

  // prologue: tile 0 -> buffer 0
#pragma unroll
  for (int i = 0; i < 4; i++) {
    GLL(kg + (size_t)i * 8 * HD, &Klds[0][sbase + i * 8 * 64]);
    GLL(vg + (size_t)i * 8 * T_, &Vt[0][sbase + i * 8 * 64]);
  }

  int cur = 0;
  for (int kt = 0; kt <= qt; kt++) {
    __syncthreads();  // drains own vmcnt(0); all waves' GLLs landed
    if (kt < qt) {    // prefetch next tile into the other buffer
      const unsigned short* kp = kg + (size_t)(kt + 1) * 64 * HD;
      const unsigned short* vp = vg + (kt + 1) * 64;
      unsigned short* kd = &Klds[cur ^ 1][sbase];
      unsigned short* vd = &Vt[cur ^ 1][sbase];
#pragma unroll
      for (int i = 0; i < 4; i++) {
        GLL(kp + (size_t)i * 8 * HD, kd + i * 8 * 64);
        GLL(vp + (size_t)i * 8 * T_, vd + i * 8 * 64);
      }
    }

    // S^T = K @ Q^T : m = key (64), n = q (32 per wave)
    f32x4 s[4][2] = {};
#pragma unroll
    for (int kk = 0; kk < 2; kk++) {
      const int cl = ((kk * 4 + quad) ^ swl) * 8;
#pragma unroll
      for (int mt = 0; mt < 4; mt++) {
        s16x8 kf = *(const s16x8*)&Klds[cur][(mt * 16 + l16) * 64 + cl];
#pragma unroll
        for (int nt = 0; nt < 2; nt++)
          s[mt][nt] = MFMA32(kf, qf[nt][kk], s[mt][nt]);
      }
    }

    // P = exp2(S) -> LDS (bf16). Row = own wave's q rows; logical 16B
    // chunk 2mt+(quad>>1), phys = ^swl, inner u32 pos (quad&1)*2.
    if (kt < qt) {  // fully visible tile: no mask code
#pragma unroll
      for (int nt = 0; nt < 2; nt++) {
        uint32_t* prow = (uint32_t*)&Plds[(wave * 32 + nt * 16 + l16) * 64];
#pragma unroll
        for (int mt = 0; mt < 4; mt++) {
          float p0 = exp2f(s[mt][nt][0]);
          float p1 = exp2f(s[mt][nt][1]);
          float p2 = exp2f(s[mt][nt][2]);
          float p3 = exp2f(s[mt][nt][3]);
          *(uint2*)&prow[(((2 * mt + (quad >> 1)) ^ swl) << 2) +
                         (quad & 1) * 2] =
              make_uint2(pk_bf16(p0, p1), pk_bf16(p2, p3));
        }
      }
    } else {  // diagonal tile: causal mask (key <= q)
#pragma unroll
      for (int nt = 0; nt < 2; nt++) {
        const int lim = wave * 32 + nt * 16 + l16;
        uint32_t* prow = (uint32_t*)&Plds[(wave * 32 + nt * 16 + l16) * 64];
#pragma unroll
        for (int mt = 0; mt < 4; mt++) {
          const int kb = mt * 16 + quad * 4;
          float p0 = (kb + 0 <= lim) ? exp2f(s[mt][nt][0]) : 0.f;
          float p1 = (kb + 1 <= lim) ? exp2f(s[mt][nt][1]) : 0.f;
          float p2 = (kb + 2 <= lim) ? exp2f(s[mt][nt][2]) : 0.f;
          float p3 = (kb + 3 <= lim) ? exp2f(s[mt][nt][3]) : 0.f;
          *(uint2*)&prow[(((2 * mt + (quad >> 1)) ^ swl) << 2) +
                         (quad & 1) * 2] =
              make_uint2(pk_bf16(p0, p1), pk_bf16(p2, p3));
        }
      }
    }

    // O += P @ V ; l += P @ 1  (same-wave P rows: no barrier needed)
#pragma unroll
    for (int kk = 0; kk < 2; kk++) {
      const int cl = ((kk * 4 + quad) ^ swl) * 8;
      s16x8 pf[2];
#pragma unroll
      for (int nt = 0; nt < 2; nt++) {
        pf[nt] =
            *(const s16x8*)&Plds[(wave * 32 + nt * 16 + l16) * 64 + cl];
        lacc[nt] = MFMA32(pf[nt], onesf, lacc[nt]);
      }
#pragma unroll
      for (int dt = 0; dt < 4; dt++) {
        s16x8 vf = *(const s16x8*)&Vt[cur][(dt * 16 + l16) * 64 + cl];
#pragma unroll
        for (int nt = 0; nt < 2; nt++)
          o[nt][dt] = MFMA32(pf[nt], vf, o[nt][dt]);
      }
    }
    cur ^= 1;
  }

  // normalize + store: lacc[nt] rows (quad*4+r) match O rows exactly
#pragma unroll
  for (int nt = 0; nt < 2; nt++) {
    f32x4 inv;
#pragma unroll
    for (int r = 0; r < 4; r++) inv[r] = 1.f / lacc[nt][r];
#pragma unroll
    for (int dt = 0; dt < 4; dt++) {
      float4 v = make_float4(o[nt][dt][0] * inv[0], o[nt][dt][1] * inv[1],
                             o[nt][dt][2] * inv[2], o[nt][dt][3] * inv[3]);
      *(float4*)(out + (size_t)bh * (HD * T_) + (size_t)(dt * 16 + l16) * T_ +
                 q0 + wave * 32 + nt * 16 + quad * 4) = v;
    }
  }
}

extern "C" void kernel_launch(void* const* d_in, const int* in_sizes, int n_in,
                              void* d_out, int out_size, void* d_ws, size_t ws_size,
                              hipStream_t stream) {
  const float* x  = (const float*)d_in[0];
  const float* wq = (const float*)d_in[1];
  const float* wk = (const float*)d_in[2];
  const float* wv = (const float*)d_in[3];
  float* out = (float*)d_out;

  unsigned short* xb  = (unsigned short*)d_ws;       // 4194304 bf16
  unsigned short* wb  = xb + 4194304;                // 3145728 bf16 [Wq;Wk;Wv]
  unsigned short* qkv = wb + 3145728;                // 3 * 4194304 bf16

  cvt_kernel<<<7168, 256, 0, stream>>>(x, wq, wk, wv, xb, wb);
  dim3 g1(24, 64);  // N/128 x M/64 -> 1536 blocks, 6/CU
  qkv_gemm<<<g1, 256, 0, stream>>>(xb, wb, qkv);
  dim3 g2(32, 32);  // bh x qt-rev (64-q tiles, descending for load balance)
  attn_kernel<<<g2, 128, 0, stream>>>(qkv, out);
}

// Round 3
// 154.174 us; speedup vs baseline: 1.0801x; 1.0801x over previous
//
#include <hip/hip_runtime.h>
#include <hip/hip_bf16.h>
#include <stdint.h>

typedef __attribute__((ext_vector_type(8))) short s16x8;
typedef __attribute__((ext_vector_type(4))) float f32x4;

#define T_   2048
#define NH   16
#define HD   64
#define DIN  1024
#define SCALE_LOG2 0.18033688011112042f  // (1/8)*log2(e)

#define MFMA32(a, b, c) __builtin_amdgcn_mfma_f32_16x16x32_bf16(a, b, c, 0, 0, 0)

// RTNE fp32 -> bf16
__device__ __forceinline__ unsigned short f2bf(float f) {
  union { float f; uint32_t u; } c; c.f = f;
  uint32_t u = c.u;
  return (unsigned short)((u + 0x7FFFu + ((u >> 16) & 1u)) >> 16);
}

__device__ __forceinline__ uint32_t pk_bf16(float a, float b) {
  __hip_bfloat162 h = __float22bfloat162_rn(make_float2(a, b));
  return *reinterpret_cast<uint32_t*>(&h);
}

// async global->LDS, 16B per lane; dest = wave-uniform base + lane*16
#define GLL(gp, lp) __builtin_amdgcn_global_load_lds( \
    (__attribute__((address_space(1))) void*)(gp),    \
    (__attribute__((address_space(3))) void*)(lp), 16, 0, 0)

// ---------------- kernel 1: fp32 -> bf16 conversion ----------------
__global__ __launch_bounds__(256) void cvt_kernel(
    const float* __restrict__ x,  const float* __restrict__ wq,
    const float* __restrict__ wk, const float* __restrict__ wv,
    unsigned short* __restrict__ xb, unsigned short* __restrict__ wb) {
  int i = (blockIdx.x * 256 + threadIdx.x) * 4;
  float4 v;
  unsigned short* dp;
  if (i < 4194304) {
    v = *(const float4*)(x + i);
    dp = xb + i;
  } else {
    int j = i - 4194304;
    int seg = j >> 20, r = j & 1048575;
    const float* w = (seg == 0) ? wq : (seg == 1) ? wk : wv;
    v = *(const float4*)(w + r);
    dp = wb + j;
  }
  ushort4 o;
  o.x = f2bf(v.x); o.y = f2bf(v.y); o.z = f2bf(v.z); o.w = f2bf(v.w);
  *(ushort4*)dp = o;
}

// ---------------- kernel 2: QKV projection GEMM ----------------
// 64x128 (MxN) tiles -> grid 24x64 = 1536 blocks = 6 blocks/CU. LDS
// 24KB/block; XOR-swizzled LDS, all-b128, GLL staging. Epilogue: Q
// pre-scaled; V transposed [bh][d][t]. (unchanged, proven)
__global__ __launch_bounds__(256) void qkv_gemm(
    const unsigned short* __restrict__ A, const unsigned short* __restrict__ Bm,
    unsigned short* __restrict__ qkv) {
  __shared__ __attribute__((aligned(16))) unsigned short Alds[64 * 64];
  __shared__ __attribute__((aligned(16))) unsigned short Blds[128 * 64];
  const int tid = threadIdx.x;
  const int lane = tid & 63, wave = tid >> 6;
  const int wm = wave >> 1, wn = wave & 1;  // 2x2 waves over 64x128
  const int m0 = blockIdx.y * 64, n0 = blockIdx.x * 128;

  f32x4 acc[2][4] = {};

  const int srA = wave * 16 + (lane >> 3);  // A staging row (2 issues x 8)
  const int srB = wave * 32 + (lane >> 3);  // B staging row (4 issues x 8)
  const int scol = (((lane & 7) ^ ((lane >> 3) & 7))) * 8;
  const unsigned short* ag = A  + (size_t)(m0 + srA) * DIN + scol;
  const unsigned short* bg = Bm + (size_t)(n0 + srB) * DIN + scol;
  unsigned short* al = &Alds[wave * 16 * 64];
  unsigned short* bl = &Blds[wave * 32 * 64];

  const int l16 = lane & 15, quad = lane >> 4;
  const int sw = l16 & 7;

  for (int k0 = 0; k0 < DIN; k0 += 64) {
    __syncthreads();
#pragma unroll
    for (int i = 0; i < 2; i++)
      GLL(ag + (size_t)i * 8 * DIN + k0, al + i * 512);
#pragma unroll
    for (int i = 0; i < 4; i++)
      GLL(bg + (size_t)i * 8 * DIN + k0, bl + i * 512);
    __syncthreads();
#pragma unroll
    for (int ks = 0; ks < 2; ks++) {
      const int cl = ((ks * 4 + quad) ^ sw) * 8;
      s16x8 af[2], bf[4];
#pragma unroll
      for (int mt = 0; mt < 2; mt++)
        af[mt] = *(const s16x8*)&Alds[(wm * 32 + mt * 16 + l16) * 64 + cl];
#pragma unroll
      for (int nt = 0; nt < 4; nt++)
        bf[nt] = *(const s16x8*)&Blds[(wn * 64 + nt * 16 + l16) * 64 + cl];
#pragma unroll
      for (int mt = 0; mt < 2; mt++)
#pragma unroll
        for (int nt = 0; nt < 4; nt++)
          acc[mt][nt] = MFMA32(af[mt], bf[nt], acc[mt][nt]);
    }
  }

#pragma unroll
  for (int mt = 0; mt < 2; mt++) {
    int mbase = m0 + wm * 32 + mt * 16 + (quad << 2);
    int b = mbase >> 11, t = mbase & 2047;
#pragma unroll
    for (int nt = 0; nt < 4; nt++) {
      int n = n0 + wn * 64 + nt * 16 + l16;
      int sel = n >> 10, h = (n >> 6) & 15, d = n & 63;
      int bh = b * NH + h;
      if (sel == 2) {
        ushort4 pk;
        pk.x = f2bf(acc[mt][nt][0]); pk.y = f2bf(acc[mt][nt][1]);
        pk.z = f2bf(acc[mt][nt][2]); pk.w = f2bf(acc[mt][nt][3]);
        *(ushort4*)&qkv[8388608 + (size_t)(bh * HD + d) * T_ + t] = pk;
      } else {
        float qs = (sel == 0) ? SCALE_LOG2 : 1.f;  // fold softmax scale into Q
#pragma unroll
        for (int r = 0; r < 4; r++)
          qkv[(size_t)sel * 4194304 + (size_t)(bh * T_ + t + r) * HD + d] =
              f2bf(acc[mt][nt][r] * qs);
      }
    }
  }
}

// ---------------- kernel 3: causal flash attention (v3: paired tiles) ------
// Round-2 counters: MfmaUtil 12 / VALUBusy 33 / HBM 6% / Occ 11.9 -> no pipe
// saturated, latency + LOAD-IMBALANCE bound. All blocks co-resident, so the
// qt-descending trick was a no-op: makespan = longest block (32 k-tiles) vs
// mean 16.5, and CUs idle through the tail.
// Fix: PAIR q-tiles {31-p, p} per block -> every block runs exactly
// (32-p)+(p+1) = 33 k-tile iterations. K/V tiles depend only on kt, so one
// flattened 33-iter loop with the proven round-7 inner body (4 waves x 16 q,
// reg-prefetch K/V double-buffer, 2 barriers/tile, XOR-swizzled 24KB LDS).
// Accumulators/Q-frags duplicated per phase, selected by block-uniform
// branch (statically indexed both sides). Grid (32 bh, 16 pairs) = 512.
__device__ __forceinline__ void tile_step(
    const unsigned short* Klds, const unsigned short* Vt,
    unsigned short* Plds, const s16x8 qf0, const s16x8 qf1,
    f32x4 o[4], f32x4& lacc,
    const int l16, const int quad, const int swl, const int wave,
    const bool diag) {
  // S^T = K @ Q^T : m = key (64), n = 16 q of this wave
  f32x4 s[4] = {};
#pragma unroll
  for (int kk = 0; kk < 2; kk++) {
    const int cl = ((kk * 4 + quad) ^ swl) * 8;
    const s16x8 q = kk ? qf1 : qf0;
#pragma unroll
    for (int mt = 0; mt < 4; mt++) {
      s16x8 kf = *(const s16x8*)&Klds[(mt * 16 + l16) * 64 + cl];
      s[mt] = MFMA32(kf, q, s[mt]);
    }
  }

  // P = exp2(S) -> LDS bf16. logical chunk 2mt+(quad>>1), phys ^swl.
  uint32_t* prow = (uint32_t*)&Plds[(wave * 16 + l16) * 64];
  if (!diag) {
#pragma unroll
    for (int mt = 0; mt < 4; mt++) {
      float p0 = exp2f(s[mt][0]);
      float p1 = exp2f(s[mt][1]);
      float p2 = exp2f(s[mt][2]);
      float p3 = exp2f(s[mt][3]);
      *(uint2*)&prow[(((2 * mt + (quad >> 1)) ^ swl) << 2) + (quad & 1) * 2] =
          make_uint2(pk_bf16(p0, p1), pk_bf16(p2, p3));
    }
  } else {  // causal mask (key <= q) on the diagonal tile
    const int lim = wave * 16 + l16;
#pragma unroll
    for (int mt = 0; mt < 4; mt++) {
      const int kb = mt * 16 + quad * 4;
      float p0 = (kb + 0 <= lim) ? exp2f(s[mt][0]) : 0.f;
      float p1 = (kb + 1 <= lim) ? exp2f(s[mt][1]) : 0.f;
      float p2 = (kb + 2 <= lim) ? exp2f(s[mt][2]) : 0.f;
      float p3 = (kb + 3 <= lim) ? exp2f(s[mt][3]) : 0.f;
      *(uint2*)&prow[(((2 * mt + (quad >> 1)) ^ swl) << 2) + (quad & 1) * 2] =
          make_uint2(pk_bf16(p0, p1), pk_bf16(p2, p3));
    }
  }

  // O += P @ V ; l += P @ 1 (same-wave P rows: compiler inserts lgkmcnt)
  const s16x8 onesf = {0x3F80, 0x3F80, 0x3F80, 0x3F80,
                       0x3F80, 0x3F80, 0x3F80, 0x3F80};
  const unsigned short* prd = &Plds[(wave * 16 + l16) * 64];
#pragma unroll
  for (int kk = 0; kk < 2; kk++) {
    const int cl = ((kk * 4 + quad) ^ swl) * 8;
    s16x8 pf = *(const s16x8*)&prd[cl];
    lacc = MFMA32(pf, onesf, lacc);
#pragma unroll
    for (int dt = 0; dt < 4; dt++) {
      s16x8 vf = *(const s16x8*)&Vt[(dt * 16 + l16) * 64 + cl];
      o[dt] = MFMA32(pf, vf, o[dt]);
    }
  }
}

__global__ __launch_bounds__(256) void attn_kernel(
    const unsigned short* __restrict__ qkv, float* __restrict__ out) {
  __shared__ __attribute__((aligned(16))) unsigned short Klds[64 * 64];
  __shared__ __attribute__((aligned(16))) unsigned short Vt[64 * 64];
  __shared__ __attribute__((aligned(16))) unsigned short Plds[64 * 64];

  const int tid = threadIdx.x;
  const int lane = tid & 63, wave = tid >> 6;
  const int l16 = lane & 15, quad = lane >> 4;
  const int swl = l16 & 7;
  const int bh = blockIdx.x;
  const int qb = blockIdx.y;        // short q-tile: qb+1 k-tiles (0..15)
  const int qa = 31 - qb;           // long q-tile: qa+1 k-tiles (16..31)
  const size_t bh_off = (size_t)bh * (T_ * HD);
  const unsigned short* Q  = qkv + bh_off;            // [t][d], pre-scaled
  const unsigned short* Kb = qkv + 4194304 + bh_off;  // [t][d]
  const unsigned short* Vb = qkv + 8388608 + bh_off;  // [d][t]

  // Q fragments for both q-tiles (16 q-rows per wave each)
  s16x8 qfa0, qfa1, qfb0, qfb1;
  {
    const unsigned short* qp =
        Q + (size_t)(qa * 64 + wave * 16 + l16) * HD + quad * 8;
    qfa0 = *(const s16x8*)(qp);
    qfa1 = *(const s16x8*)(qp + 32);
    const unsigned short* qq =
        Q + (size_t)(qb * 64 + wave * 16 + l16) * HD + quad * 8;
    qfb0 = *(const s16x8*)(qq);
    qfb1 = *(const s16x8*)(qq + 32);
  }

  // K/V staging (proven round-7): reg prefetch, XOR-swizzled LDS write
  const int sr = tid >> 3;                 // staging row 0..31
  const int sc = (tid & 7) * 8;            // linear global chunk
  const int swc = (((tid & 7) ^ (sr & 7))) * 8;  // swizzled LDS chunk

  s16x8 kr0 = *(const s16x8*)&Kb[(size_t)sr * HD + sc];
  s16x8 kr1 = *(const s16x8*)&Kb[(size_t)(sr + 32) * HD + sc];
  s16x8 vr0 = *(const s16x8*)&Vb[(size_t)sr * T_ + sc];
  s16x8 vr1 = *(const s16x8*)&Vb[(size_t)(sr + 32) * T_ + sc];

  f32x4 oa[4] = {}, ob[4] = {};
  f32x4 la = {}, lb = {};

  // flat sequence of 33 k-tiles: kt = 0..qa (phase a), then 0..qb (phase b)
  for (int it = 0; it < 33; it++) {
    const bool pa = (it <= qa);
    __syncthreads();
    *(s16x8*)&Klds[sr * 64 + swc] = kr0;
    *(s16x8*)&Klds[(sr + 32) * 64 + swc] = kr1;
    *(s16x8*)&Vt[sr * 64 + swc] = vr0;
    *(s16x8*)&Vt[(sr + 32) * 64 + swc] = vr1;
    if (it < 32) {  // prefetch next kt in the flat sequence
      const int nk = (it < qa) ? it + 1 : it - qa;
      const unsigned short* kp = Kb + (size_t)nk * 64 * HD;
      const unsigned short* vp = Vb + nk * 64;
      kr0 = *(const s16x8*)&kp[(size_t)sr * HD + sc];
      kr1 = *(const s16x8*)&kp[(size_t)(sr + 32) * HD + sc];
      vr0 = *(const s16x8*)&vp[(size_t)sr * T_ + sc];
      vr1 = *(const s16x8*)&vp[(size_t)(sr + 32) * T_ + sc];
    }
    __syncthreads();

    if (pa)
      tile_step(Klds, Vt, Plds, qfa0, qfa1, oa, la, l16, quad, swl, wave,
                it == qa);
    else
      tile_step(Klds, Vt, Plds, qfb0, qfb1, ob, lb, l16, quad, swl, wave,
                it == 32);
  }

  // normalize + store both q-tiles: lacc rows (quad*4+r) match O rows
#pragma unroll
  for (int half = 0; half < 2; half++) {
    const f32x4* o = half ? ob : oa;
    const f32x4 lacc = half ? lb : la;
    const int q0 = (half ? qb : qa) * 64;
    f32x4 inv;
#pragma unroll
    for (int r = 0; r < 4; r++) inv[r] = 1.f / lacc[r];
#pragma unroll
    for (int dt = 0; dt < 4; dt++) {
      float4 v = make_float4(o[dt][0] * inv[0], o[dt][1] * inv[1],
                             o[dt][2] * inv[2], o[dt][3] * inv[3]);
      *(float4*)(out + (size_t)bh * (HD * T_) + (size_t)(dt * 16 + l16) * T_ +
                 q0 + wave * 16 + quad * 4) = v;
    }
  }
}

extern "C" void kernel_launch(void* const* d_in, const int* in_sizes, int n_in,
                              void* d_out, int out_size, void* d_ws, size_t ws_size,
                              hipStream_t stream) {
  const float* x  = (const float*)d_in[0];
  const float* wq = (const float*)d_in[1];
  const float* wk = (const float*)d_in[2];
  const float* wv = (const float*)d_in[3];
  float* out = (float*)d_out;

  unsigned short* xb  = (unsigned short*)d_ws;       // 4194304 bf16
  unsigned short* wb  = xb + 4194304;                // 3145728 bf16 [Wq;Wk;Wv]
  unsigned short* qkv = wb + 3145728;                // 3 * 4194304 bf16

  cvt_kernel<<<7168, 256, 0, stream>>>(x, wq, wk, wv, xb, wb);
  dim3 g1(24, 64);  // N/128 x M/64 -> 1536 blocks, 6/CU
  qkv_gemm<<<g1, 256, 0, stream>>>(xb, wb, qkv);
  dim3 g2(32, 16);  // bh x pair -> 512 blocks, each exactly 33 k-tile iters
  attn_kernel<<<g2, 256, 0, stream>>>(qkv, out);
}